// Round 4
// baseline (323.219 us; speedup 1.0000x reference)
//
#include <hip/hip_runtime.h>
#include <cmath>

#define NB   2048
#define ND   512
#define NL   8
#define NLAB 128
#define MAXM 64
#define TOPK_ 5
#define NTH  256
#define MAXSLOT 9            // ceil(64*65/2 / 256)
#define GSTRIDE (MAXM*MAXM)  // 4096 floats per (label,layer) gram

// ---------------------------------------------------------------------------
// R15. R14 post-mortem: spin grid-barrier deadlocked (co-residency of 1024
// blocks NOT guaranteed at 132 VGPR -> 2 blocks/CU) and killed the container.
// Rule: no spin-waits, ever. This version is a single kernel with FAN-IN
// dependencies only (last-arriving block continues; nobody waits):
//   Phase A (all 1024 blocks, grid (128,8)): R13 k_gram verbatim -- gram +
//     normalize in LDS, store normalized G, layer-7 blocks do phase-1 insub.
//   Fan-in per label c: __threadfence + atomicAdd(done[c]); the 8th arriver
//     streams the 8 tiles through a double-buffered LDS pair, runs decide(l)
//     per layer (R13 wave-0 code, bit-identical) and pair(p) p=0..6 with the
//     exact R13 reduce order -> partial[p][c]. Overlaps with other labels'
//     gram blocks still running.
//   Fan-in over 128 label-finishers: last one runs k_final's exact code.
// Counters are zero-init self-resetting __device__ globals (workspace is
// poisoned per-iteration, so counters must NOT live there).
// All FP op order identical to the passing R13 -> absmax 0.0.
// ---------------------------------------------------------------------------

__device__ unsigned g_done[NLAB * 16];   // 64B-strided per-label arrival counters
__device__ unsigned g_fin;               // label-finisher counter

#define SLOT_DECL(s) int off##s = -1; int lds##s = 0; float4 pre##s;
#define SLOT_INIT(s) { int idx = tid + (s)*NTH; if (idx < (m << 5)) { \
    int i = idx >> 5, k4 = idx & 31; \
    off##s = (g_s[i] << 9) + (k4 << 2); \
    lds##s = i * 132 + (k4 << 2); \
    pre##s = *(const float4*)(X + off##s); } }
#define SLOT_STORE(s) if (off##s >= 0) *(float4*)(XtF + lds##s) = pre##s;
#define SLOT_FETCH(s, kcn) if (off##s >= 0) pre##s = *(const float4*)(X + off##s + (kcn));

__global__ __launch_bounds__(NTH) void k_gramfan(
    const float* __restrict__ feats, const int* __restrict__ labels,
    float* __restrict__ G, unsigned long long* __restrict__ insub,
    float* __restrict__ partial, float* __restrict__ out)
{
    __shared__ int wsum[4];
    __shared__ int g_s[MAXM];
    __shared__ float Xt[MAXM][132];   // 33792 B; phase B overlays two [64][65] tiles
    __shared__ float rinvp[64];
    __shared__ unsigned long long tops_s[64];
    __shared__ unsigned char keep_s[64];
    __shared__ unsigned long long Ml[NL][64];
    __shared__ float El[NL][64];
    __shared__ float red[12];
    __shared__ int sh_prev;
    float* XtF = &Xt[0][0];
    int c = blockIdx.x, l = blockIdx.y, tid = threadIdx.x;
    int lane = tid & 63, wv = tid >> 6;

    // ================= Phase A: gram(c,l) + normalize (+phase-1 l==7) =======
    int my[8]; int n = 0; int base_i = tid * 8;
    for (int t = 0; t < 8; ++t) {
        int i = base_i + t;
        if (labels[i] == c) my[n++] = i;
    }
    int scan = n;
    #pragma unroll
    for (int off = 1; off < 64; off <<= 1) {
        int v = __shfl_up(scan, off);
        if (lane >= off) scan += v;
    }
    if (lane == 63) wsum[wv] = scan;
    __syncthreads();
    int w0 = wsum[0], w1 = wsum[1], w2 = wsum[2], w3 = wsum[3];
    int m = w0 + w1 + w2 + w3; if (m > MAXM) m = MAXM;
    int base = (wv > 0 ? w0 : 0) + (wv > 1 ? w1 : 0) + (wv > 2 ? w2 : 0);
    int excl = base + scan - n;
    for (int t = 0; t < n; ++t) {
        int slot = excl + t;
        if (slot < MAXM) g_s[slot] = my[t];
    }
    __syncthreads();

    if (m > 0) {
        const float* X = feats + (size_t)l * NB * ND;

        SLOT_DECL(0) SLOT_DECL(1) SLOT_DECL(2) SLOT_DECL(3)
        SLOT_DECL(4) SLOT_DECL(5) SLOT_DECL(6) SLOT_DECL(7)
        SLOT_INIT(0) SLOT_INIT(1) SLOT_INIT(2) SLOT_INIT(3)
        SLOT_INIT(4) SLOT_INIT(5) SLOT_INIT(6) SLOT_INIT(7)

        const int P = m * (m + 1) / 2;
        float acc0[MAXSLOT], acc1[MAXSLOT];
        short is_[MAXSLOT], js_[MAXSLOT];
        int ns = 0;
        for (int p = tid; p < P; p += NTH) {
            int i = (int)((sqrtf(8.0f * (float)p + 1.0f) - 1.0f) * 0.5f);
            while (((i + 1) * (i + 2)) / 2 <= p) ++i;
            while ((i * (i + 1)) / 2 > p) --i;
            is_[ns] = (short)i;
            js_[ns] = (short)(p - (i * (i + 1)) / 2);
            acc0[ns] = 0.0f; acc1[ns] = 0.0f;
            ++ns;
        }

        for (int kc = 0; kc < ND; kc += 128) {
            if (kc) __syncthreads();
            SLOT_STORE(0) SLOT_STORE(1) SLOT_STORE(2) SLOT_STORE(3)
            SLOT_STORE(4) SLOT_STORE(5) SLOT_STORE(6) SLOT_STORE(7)
            __syncthreads();
            if (kc + 128 < ND) {
                int kcn = kc + 128;
                SLOT_FETCH(0, kcn) SLOT_FETCH(1, kcn) SLOT_FETCH(2, kcn) SLOT_FETCH(3, kcn)
                SLOT_FETCH(4, kcn) SLOT_FETCH(5, kcn) SLOT_FETCH(6, kcn) SLOT_FETCH(7, kcn)
            }
            for (int s = 0; s < ns; ++s) {
                int i = is_[s], j = js_[s];
                float a0 = acc0[s], a1 = acc1[s];
                #pragma unroll
                for (int k4 = 0; k4 < 32; ++k4) {
                    float4 a = *(const float4*)&Xt[i][k4 << 2];
                    float4 b = *(const float4*)&Xt[j][k4 << 2];
                    a0 = fmaf(a.x, b.x, a0); a1 = fmaf(a.y, b.y, a1);
                    a0 = fmaf(a.z, b.z, a0); a1 = fmaf(a.w, b.w, a1);
                }
                acc0[s] = a0; acc1[s] = a1;
            }
        }

        float (*Gs)[65] = (float(*)[65])(&Xt[0][0]);
        __syncthreads();
        for (int s = 0; s < ns; ++s) {
            int i = is_[s], j = js_[s];
            float v = acc0[s] + acc1[s];
            Gs[i][j] = v; Gs[j][i] = v;
        }
        if (tid < m) for (int j = m; j < 64; ++j) Gs[tid][j] = -2.0f;
        __syncthreads();
        if (tid < 64) rinvp[tid] = (tid < m) ? 1.0f / fmaxf(sqrtf(Gs[tid][tid]), 1e-8f) : 0.0f;
        __syncthreads();
        // normalize+clip in place: clip((raw*ri)*rj) -- exact op order
        for (int idx = tid; idx < (m << 6); idx += NTH) {
            int i = idx >> 6, j = idx & 63;
            if (j < m) {
                float raw = Gs[i][j];
                Gs[i][j] = fminf(fmaxf(raw * rinvp[i] * rinvp[j], -1.0f), 1.0f);
            }
        }
        __syncthreads();
        float* Gc = G + ((size_t)l * NLAB + c) * GSTRIDE;
        for (int idx4 = tid; idx4 < (m << 4); idx4 += NTH) {
            int i = idx4 >> 4, j0 = (idx4 & 15) << 2;
            *(float4*)(Gc + i * MAXM + j0) = *(const float4*)&Gs[i][j0];
        }

        if (l == 7) {
            // ---- phase-1: full-group knn on normalized tile -> insub ----
            if (tid < 64) { keep_s[tid] = 0; tops_s[tid] = 0ull; }
            __syncthreads();
            unsigned long long tops = 0ull; bool keep = false;
            if (tid < m) {
                float v0=-1.f,v1=-1.f,v2=-1.f,v3=-1.f,v4=-1.f;
                int i0=0,i1=0,i2=0,i3=0,i4=0, cand=0;
                #pragma unroll 8
                for (int j = 0; j < 64; ++j) {
                    float v = Gs[tid][j];
                    if (v > 0.0f && j != tid) {
                        ++cand;
                        if      (v > v0) { v4=v3;i4=i3; v3=v2;i3=i2; v2=v1;i2=i1; v1=v0;i1=i0; v0=v;i0=j; }
                        else if (v > v1) { v4=v3;i4=i3; v3=v2;i3=i2; v2=v1;i2=i1; v1=v;i1=j; }
                        else if (v > v2) { v4=v3;i4=i3; v3=v2;i3=i2; v2=v;i2=j; }
                        else if (v > v3) { v4=v3;i4=i3; v3=v;i3=j; }
                        else if (v > v4) { v4=v;i4=j; }
                    }
                }
                keep = (cand >= TOPK_);
                if (keep) tops = (1ull<<i0)|(1ull<<i1)|(1ull<<i2)|(1ull<<i3)|(1ull<<i4);
                keep_s[tid] = keep ? 1 : 0; tops_s[tid] = tops;
            }
            __syncthreads();
            unsigned long long Mrow = 0ull;
            if (tid < m && keep) {
                for (int j = 0; j < 64; ++j) {
                    if (j == tid || !keep_s[j]) continue;
                    if (((tops >> j) & 1ull) || ((tops_s[j] >> tid) & 1ull)) Mrow |= (1ull << j);
                }
            }
            if (tid < 64) {
                unsigned long long b = __ballot(Mrow != 0ull);
                if (tid == 0) insub[c] = b;
            }
        }
    } else {
        if (l == 7 && tid == 0) insub[c] = 0ull;
    }

    // ================= Fan-in per label: 8th arriver continues ==============
    __threadfence();                 // every thread releases its own stores
    __syncthreads();                 // all fences done before the arrive
    if (tid == 0) {
        unsigned prev = __hip_atomic_fetch_add(&g_done[c * 16], 1u,
                            __ATOMIC_ACQ_REL, __HIP_MEMORY_SCOPE_AGENT);
        sh_prev = (int)prev;
        if (prev == NL - 1)          // reset for next graph replay
            __hip_atomic_store(&g_done[c * 16], 0u, __ATOMIC_RELAXED, __HIP_MEMORY_SCOPE_AGENT);
    }
    __syncthreads();
    if (sh_prev != NL - 1) return;   // non-last blocks exit (no waiting!)
    __threadfence();                 // acquire side

    // ================= Phase B (one block per label) ========================
    float (*B0)[65] = (float(*)[65])(XtF);
    float (*B1)[65] = (float(*)[65])(XtF + 4160);
    unsigned long long sub = insub[c];

    for (int lp = 0; lp < NL; ++lp) {
        float (*Gt)[65] = (lp & 1) ? B1 : B0;
        const float* Gl = G + ((size_t)lp * NLAB + c) * GSTRIDE;
        __syncthreads();             // prior readers of this buffer done
        for (int idx4 = tid; idx4 < (m << 4); idx4 += NTH) {
            int i = idx4 >> 4, j0 = (idx4 & 15) << 2;
            *(float4*)&Gt[i][j0] = *(const float4*)(Gl + i * MAXM + j0);
        }
        if (tid < 64) { keep_s[tid] = 0; tops_s[tid] = 0ull; }
        __syncthreads();

        // ---- decide(lp) on wave 0 (R13 code, bit-identical) ----
        unsigned long long tops = 0ull; bool keep = false;
        if (wv == 0 && lane < m) {
            bool act = (sub >> lane) & 1ull;
            float emaval = 0.0f;
            if (act) {
                float v0=-1.f,v1=-1.f,v2=-1.f,v3=-1.f,v4=-1.f;
                int i0=0,i1=0,i2=0,i3=0,i4=0, cand=0, dg=0;
                float rs = 0.0f;
                #pragma unroll 8
                for (int j = 0; j < 64; ++j) {
                    float v = Gt[lane][j];
                    if (!((sub >> j) & 1ull)) v = -2.0f;
                    if (v > 0.0f) {
                        rs += v; ++dg;              // includes j == lane (diag ~ 1.0)
                        if (j != lane) {
                            ++cand;
                            if      (v > v0) { v4=v3;i4=i3; v3=v2;i3=i2; v2=v1;i2=i1; v1=v0;i1=i0; v0=v;i0=j; }
                            else if (v > v1) { v4=v3;i4=i3; v3=v2;i3=i2; v2=v1;i2=i1; v1=v;i1=j; }
                            else if (v > v2) { v4=v3;i4=i3; v3=v2;i3=i2; v2=v;i2=j; }
                            else if (v > v3) { v4=v3;i4=i3; v3=v;i3=j; }
                            else if (v > v4) { v4=v;i4=j; }
                        }
                    }
                }
                keep = (cand >= TOPK_);
                if (keep) tops = (1ull<<i0)|(1ull<<i1)|(1ull<<i2)|(1ull<<i3)|(1ull<<i4);
                float deg = (float)(dg > 0 ? dg : 1);
                float score = 1.0f / (1.0f + expf(-rs / deg));
                emaval = 0.45f + 0.1f * score;      // MOM*0.5 + (1-MOM)*score
            }
            keep_s[lane] = keep ? 1 : 0; tops_s[lane] = tops;
            El[lp][lane] = emaval;
        }
        __syncthreads();
        if (wv == 0 && lane < m) {
            unsigned long long Mrow = 0ull;
            if (keep) {
                for (int j = 0; j < 64; ++j) {
                    if (j == lane || !keep_s[j]) continue;
                    if (((tops >> j) & 1ull) || ((tops_s[j] >> lane) & 1ull)) Mrow |= (1ull << j);
                }
            }
            Ml[lp][lane] = Mrow;
        }
        __syncthreads();

        // ---- pair(lp-1): tiles lp-1,lp resident (R13 reduce, bit-identical) ----
        if (lp >= 1) {
            int p = lp - 1;
            const float (*Bp)[65]  = (p & 1) ? B1 : B0;
            const float (*Bp1)[65] = (p & 1) ? B0 : B1;
            float fn = 0.0f, fd = 0.0f, fc = 0.0f;
            for (int idx = tid; idx < (m << 6); idx += NTH) {
                int i = idx >> 6, j = idx & 63;
                if (j >= m) continue;
                bool b0 = (Ml[p][i] >> j) & 1ull;
                bool b1 = (Ml[p + 1][i] >> j) & 1ull;
                if (b0 | b1) {
                    float v0 = b0 ? Bp[i][j] : 0.0f;
                    float v1 = b1 ? Bp1[i][j] : 0.0f;
                    float w = El[p][i] * El[p][j];
                    float d = v1 - v0;
                    fn = fmaf(d * d, w, fn);
                    fd += w;
                    fc += 1.0f;
                }
            }
            for (int off = 32; off > 0; off >>= 1) {
                fn += __shfl_down(fn, off);
                fd += __shfl_down(fd, off);
                fc += __shfl_down(fc, off);
            }
            if ((tid & 63) == 0) { red[wv * 3] = fn; red[wv * 3 + 1] = fd; red[wv * 3 + 2] = fc; }
            __syncthreads();
            if (tid == 0) {
                float* dst = partial + ((size_t)p * NLAB + c) * 4;
                dst[0] = red[0] + red[3] + red[6] + red[9];
                dst[1] = red[1] + red[4] + red[7] + red[10];
                dst[2] = red[2] + red[5] + red[8] + red[11];
            }
            __syncthreads();
        }
    }

    // ================= Fan-in over labels: 128th runs the final =============
    __threadfence();
    __syncthreads();
    if (tid == 0) {
        unsigned pf = __hip_atomic_fetch_add(&g_fin, 1u,
                          __ATOMIC_ACQ_REL, __HIP_MEMORY_SCOPE_AGENT);
        sh_prev = (int)pf;
        if (pf == NLAB - 1)
            __hip_atomic_store(&g_fin, 0u, __ATOMIC_RELAXED, __HIP_MEMORY_SCOPE_AGENT);
    }
    __syncthreads();
    if (sh_prev != NLAB - 1) return;
    __threadfence();

    // k_final body, exact summation order
    if (tid < 64) {
        float total = 0.0f;
        for (int p = 0; p < NL - 1; ++p) {
            float nn = 0.0f, d = 0.0f, cc = 0.0f;
            for (int ci = tid; ci < NLAB; ci += 64) {
                const float* src = partial + ((size_t)p * NLAB + ci) * 4;
                nn += src[0]; d += src[1]; cc += src[2];
            }
            for (int off = 32; off > 0; off >>= 1) {
                nn += __shfl_down(nn, off);
                d += __shfl_down(d, off);
                cc += __shfl_down(cc, off);
            }
            if (tid == 0 && cc > 0.0f) total += nn / fmaxf(d, 1e-8f);
        }
        if (tid == 0) out[0] = 16.0f * total / 7.0f;   // LAMBDA_ALIGN_K * sum / (L-1)
    }
}

extern "C" void kernel_launch(void* const* d_in, const int* in_sizes, int n_in,
                              void* d_out, int out_size, void* d_ws, size_t ws_size,
                              hipStream_t stream) {
    const float* feats  = (const float*)d_in[0];
    const int*   labels = (const int*)d_in[1];
    // (sample_ids unused by the reference)
    char* w = (char*)d_ws;
    size_t gbytes = (size_t)NL * NLAB * GSTRIDE * 4;                 // 16,777,216
    float*    G       = (float*)(w);                                 // normalized grams
    float*    partial = (float*)(w + gbytes);                        // 14,336 B
    unsigned long long* insub = (unsigned long long*)(w + gbytes + 14336 + 512); // 8B-aligned
    float*    out     = (float*)d_out;

    k_gramfan<<<dim3(NLAB, NL), NTH, 0, stream>>>(feats, labels, G, insub, partial, out);
}

// Round 5
// 141.073 us; speedup vs baseline: 2.2912x; 2.2912x over previous
//
#include <hip/hip_runtime.h>
#include <cmath>

#define NB   2048
#define ND   512
#define NL   8
#define NLAB 128
#define MAXM 64
#define TOPK_ 5
#define NTH  256
#define MAXSLOT 9            // ceil(64*65/2 / 256)
#define GSTRIDE (MAXM*MAXM)  // 4096 floats per (label,layer) gram

// ---------------------------------------------------------------------------
// R16. Post-mortems: R14 spin barrier -> container kill; R15 fan-in fences ->
// 268us (per-block device-scope fences serialize L2 writeback/invalidate on
// non-coherent per-XCD L2s). RULE: cross-block data flow only across kernel
// launches. Keep R13's proven 3-launch shape; attack k_gram's dominance:
//   k_gram2, grid (128,4): each block computes TWO layers (2g, 2g+1) --
//   bucket scan + triangular decode + slot offsets computed ONCE (label-
//   dependent only), 512 blocks instead of 1024 (half dispatch overhead),
//   layer-A gram lands in a separate GsA tile so its epilogue can't collide
//   with layer-B staging in Xt. LDS ~52KB -> 3 blocks/CU -> all co-resident.
// All FP op order identical to passing R13 -> absmax 0.0.
// SQ_LDS_BANK_CONFLICT measured ~129K cycles aggregate (~0.05us/CU): bank
// conflicts are a non-issue; no swizzle needed.
// ---------------------------------------------------------------------------
#define SLOT_DECL(s) int off##s = -1; int lds##s = 0; float4 pre##s;
#define SLOT_SETUP(s) { int idx = tid + (s)*NTH; if (idx < (m << 5)) { \
    int i = idx >> 5, k4 = idx & 31; \
    off##s = (g_s[i] << 9) + (k4 << 2); \
    lds##s = i * 132 + (k4 << 2); } }
#define SLOT_FETCH(s, xb, kcn) if (off##s >= 0) pre##s = *(const float4*)((xb) + off##s + (kcn));
#define SLOT_STORE(s) if (off##s >= 0) *(float4*)(XtF + lds##s) = pre##s;

__global__ __launch_bounds__(NTH) void k_gram2(
    const float* __restrict__ feats, const int* __restrict__ labels,
    float* __restrict__ G, int* __restrict__ cnt,
    unsigned long long* __restrict__ insub)
{
    __shared__ int wsum[4];
    __shared__ int g_s[MAXM];
    __shared__ float Xt[MAXM][132];   // staging; reused as layer-B gram tile [64][65]
    __shared__ float GsA[MAXM][65];   // layer-A gram tile (epilogue overlaps B staging)
    __shared__ float rinvp[64];
    __shared__ unsigned long long tops_s[64];
    __shared__ unsigned char keep_s[64];
    float* XtF = &Xt[0][0];
    int c = blockIdx.x, g = blockIdx.y, tid = threadIdx.x;
    int lane = tid & 63, wv = tid >> 6;

    // ---- bucket via wave scan (deterministic, index-ascending) -- ONCE ----
    int my[8]; int n = 0; int base_i = tid * 8;
    for (int t = 0; t < 8; ++t) {
        int i = base_i + t;
        if (labels[i] == c) my[n++] = i;
    }
    int scan = n;
    #pragma unroll
    for (int off = 1; off < 64; off <<= 1) {
        int v = __shfl_up(scan, off);
        if (lane >= off) scan += v;
    }
    if (lane == 63) wsum[wv] = scan;
    __syncthreads();
    int w0 = wsum[0], w1 = wsum[1], w2 = wsum[2], w3 = wsum[3];
    int m = w0 + w1 + w2 + w3; if (m > MAXM) m = MAXM;
    int base = (wv > 0 ? w0 : 0) + (wv > 1 ? w1 : 0) + (wv > 2 ? w2 : 0);
    int excl = base + scan - n;
    for (int t = 0; t < n; ++t) {
        int slot = excl + t;
        if (slot < MAXM) g_s[slot] = my[t];
    }
    if (g == 0 && tid == 0) cnt[c] = m;
    __syncthreads();
    if (m == 0) {
        if (g == 3 && tid == 0) insub[c] = 0ull;
        return;
    }

    // ---- slot offsets + triangular decode -- ONCE (layer-independent) ----
    SLOT_DECL(0) SLOT_DECL(1) SLOT_DECL(2) SLOT_DECL(3)
    SLOT_DECL(4) SLOT_DECL(5) SLOT_DECL(6) SLOT_DECL(7)
    SLOT_SETUP(0) SLOT_SETUP(1) SLOT_SETUP(2) SLOT_SETUP(3)
    SLOT_SETUP(4) SLOT_SETUP(5) SLOT_SETUP(6) SLOT_SETUP(7)

    const int P = m * (m + 1) / 2;    // triangular incl. diag
    float acc0[MAXSLOT], acc1[MAXSLOT];
    short is_[MAXSLOT], js_[MAXSLOT];
    int ns = 0;
    for (int p = tid; p < P; p += NTH) {
        int i = (int)((sqrtf(8.0f * (float)p + 1.0f) - 1.0f) * 0.5f);
        while (((i + 1) * (i + 2)) / 2 <= p) ++i;
        while ((i * (i + 1)) / 2 > p) --i;
        is_[ns] = (short)i;
        js_[ns] = (short)(p - (i * (i + 1)) / 2);
        ++ns;
    }

    for (int half = 0; half < 2; ++half) {
        int l = (g << 1) + half;
        const float* X = feats + (size_t)l * NB * ND;

        for (int s = 0; s < ns; ++s) { acc0[s] = 0.0f; acc1[s] = 0.0f; }
        // prefetch chunk 0 of this layer
        SLOT_FETCH(0, X, 0) SLOT_FETCH(1, X, 0) SLOT_FETCH(2, X, 0) SLOT_FETCH(3, X, 0)
        SLOT_FETCH(4, X, 0) SLOT_FETCH(5, X, 0) SLOT_FETCH(6, X, 0) SLOT_FETCH(7, X, 0)

        // ---- pipelined K-loop (exact R13 structure & FMA order) ----
        for (int kc = 0; kc < ND; kc += 128) {
            if (kc) __syncthreads();      // previous chunk's readers done
            SLOT_STORE(0) SLOT_STORE(1) SLOT_STORE(2) SLOT_STORE(3)
            SLOT_STORE(4) SLOT_STORE(5) SLOT_STORE(6) SLOT_STORE(7)
            __syncthreads();
            if (kc + 128 < ND) {
                int kcn = kc + 128;
                SLOT_FETCH(0, X, kcn) SLOT_FETCH(1, X, kcn) SLOT_FETCH(2, X, kcn) SLOT_FETCH(3, X, kcn)
                SLOT_FETCH(4, X, kcn) SLOT_FETCH(5, X, kcn) SLOT_FETCH(6, X, kcn) SLOT_FETCH(7, X, kcn)
            }
            for (int s = 0; s < ns; ++s) {
                int i = is_[s], j = js_[s];
                float a0 = acc0[s], a1 = acc1[s];
                #pragma unroll
                for (int k4 = 0; k4 < 32; ++k4) {
                    float4 a = *(const float4*)&Xt[i][k4 << 2];
                    float4 b = *(const float4*)&Xt[j][k4 << 2];
                    a0 = fmaf(a.x, b.x, a0); a1 = fmaf(a.y, b.y, a1);
                    a0 = fmaf(a.z, b.z, a0); a1 = fmaf(a.w, b.w, a1);
                }
                acc0[s] = a0; acc1[s] = a1;
            }
        }

        // ---- epilogue: gram tile -> normalize -> store (exact R13 order) ----
        // half 0 -> GsA (so Xt is free for half-1 staging); half 1 -> Xt reuse.
        float (*Gs)[65] = (half == 0) ? GsA : (float(*)[65])(&Xt[0][0]);
        __syncthreads();                  // all Xt readers done
        for (int s = 0; s < ns; ++s) {
            int i = is_[s], j = js_[s];
            float v = acc0[s] + acc1[s];
            Gs[i][j] = v; Gs[j][i] = v;
        }
        if (tid < m) for (int j = m; j < 64; ++j) Gs[tid][j] = -2.0f;  // sentinel cols
        __syncthreads();
        if (tid < 64) rinvp[tid] = (tid < m) ? 1.0f / fmaxf(sqrtf(Gs[tid][tid]), 1e-8f) : 0.0f;
        __syncthreads();
        // normalize+clip in place: clip((raw*ri)*rj) -- exact op order
        for (int idx = tid; idx < (m << 6); idx += NTH) {
            int i = idx >> 6, j = idx & 63;
            if (j < m) {
                float raw = Gs[i][j];
                Gs[i][j] = fminf(fmaxf(raw * rinvp[i] * rinvp[j], -1.0f), 1.0f);
            }
        }
        __syncthreads();
        float* Gc = G + ((size_t)l * NLAB + c) * GSTRIDE;
        for (int idx4 = tid; idx4 < (m << 4); idx4 += NTH) {
            int i = idx4 >> 4, j0 = (idx4 & 15) << 2;
            *(float4*)(Gc + i * MAXM + j0) = *(const float4*)&Gs[i][j0];
        }

        if (half == 1 && l == 7) {
            // ---- fused phase-1 from normalized tile (exact R13) ----
            if (tid < 64) { keep_s[tid] = 0; tops_s[tid] = 0ull; }
            __syncthreads();
            unsigned long long tops = 0ull; bool keep = false;
            if (tid < m) {
                float v0=-1.f,v1=-1.f,v2=-1.f,v3=-1.f,v4=-1.f;
                int i0=0,i1=0,i2=0,i3=0,i4=0, cand=0;
                #pragma unroll 8
                for (int j = 0; j < 64; ++j) {
                    float v = Gs[tid][j];          // normalized, or -2 sentinel
                    if (v > 0.0f && j != tid) {
                        ++cand;
                        if      (v > v0) { v4=v3;i4=i3; v3=v2;i3=i2; v2=v1;i2=i1; v1=v0;i1=i0; v0=v;i0=j; }
                        else if (v > v1) { v4=v3;i4=i3; v3=v2;i3=i2; v2=v1;i2=i1; v1=v;i1=j; }
                        else if (v > v2) { v4=v3;i4=i3; v3=v2;i3=i2; v2=v;i2=j; }
                        else if (v > v3) { v4=v3;i4=i3; v3=v;i3=j; }
                        else if (v > v4) { v4=v;i4=j; }
                    }
                }
                keep = (cand >= TOPK_);
                if (keep) tops = (1ull<<i0)|(1ull<<i1)|(1ull<<i2)|(1ull<<i3)|(1ull<<i4);
                keep_s[tid] = keep ? 1 : 0; tops_s[tid] = tops;
            }
            __syncthreads();
            unsigned long long Mrow = 0ull;
            if (tid < m && keep) {
                for (int j = 0; j < 64; ++j) {
                    if (j == tid || !keep_s[j]) continue;
                    if (((tops >> j) & 1ull) || ((tops_s[j] >> tid) & 1ull)) Mrow |= (1ull << j);
                }
            }
            if (tid < 64) {
                unsigned long long b = __ballot(Mrow != 0ull);
                if (tid == 0) insub[c] = b;
            }
        }
    }
}

// ---------------------------------------------------------------------------
// Per (label, pair p): load normalized tiles p,p+1; decide(p) on wave 0 and
// decide(p+1) on wave 1 concurrently; masked pair reduce from LDS. (R13.)
// ---------------------------------------------------------------------------
__global__ __launch_bounds__(NTH) void k_pairdec(
    const float* __restrict__ G, const int* __restrict__ cnt,
    const unsigned long long* __restrict__ insub,
    float* __restrict__ partial)   // [NL-1][NLAB][4]
{
    __shared__ float Gs0[64][65];
    __shared__ float Gs1[64][65];
    __shared__ unsigned long long tops0[64], tops1[64];
    __shared__ unsigned char keep0[64], keep1[64];
    __shared__ unsigned long long M0s[64], M1s[64];
    __shared__ float es[64];
    __shared__ float red[12];      // 4 waves x 3
    int c = blockIdx.x, p = blockIdx.y, tid = threadIdx.x;
    int lane = tid & 63, wv = tid >> 6;
    int m = cnt[c]; if (m > MAXM) m = MAXM;
    unsigned long long sub = insub[c];

    const float* G0 = G + ((size_t)p       * NLAB + c) * GSTRIDE;
    const float* G1 = G + ((size_t)(p + 1) * NLAB + c) * GSTRIDE;
    for (int idx4 = tid; idx4 < (m << 4); idx4 += NTH) {
        int i = idx4 >> 4, j0 = (idx4 & 15) << 2;
        *(float4*)&Gs0[i][j0] = *(const float4*)(G0 + i * MAXM + j0);
        *(float4*)&Gs1[i][j0] = *(const float4*)(G1 + i * MAXM + j0);
    }
    if (tid < 64)       { keep0[tid] = 0; tops0[tid] = 0ull; }
    else if (tid < 128) { keep1[tid - 64] = 0; tops1[tid - 64] = 0ull; }
    __syncthreads();

    // ---- decide: wave 0 -> layer p (also ema), wave 1 -> layer p+1 ----
    unsigned long long tops = 0ull; bool keep = false;
    if (wv < 2 && lane < m) {
        const float (*Gt)[65] = (wv == 0) ? Gs0 : Gs1;
        bool act = (sub >> lane) & 1ull;
        float emaval = 0.0f;
        if (act) {
            float v0=-1.f,v1=-1.f,v2=-1.f,v3=-1.f,v4=-1.f;
            int i0=0,i1=0,i2=0,i3=0,i4=0, cand=0, dg=0;
            float rs = 0.0f;
            #pragma unroll 8
            for (int j = 0; j < 64; ++j) {
                float v = Gt[lane][j];
                if (!((sub >> j) & 1ull)) v = -2.0f;
                if (v > 0.0f) {
                    rs += v; ++dg;                  // includes j == lane (diag ~ 1.0)
                    if (j != lane) {
                        ++cand;
                        if      (v > v0) { v4=v3;i4=i3; v3=v2;i3=i2; v2=v1;i2=i1; v1=v0;i1=i0; v0=v;i0=j; }
                        else if (v > v1) { v4=v3;i4=i3; v3=v2;i3=i2; v2=v1;i2=i1; v1=v;i1=j; }
                        else if (v > v2) { v4=v3;i4=i3; v3=v2;i3=i2; v2=v;i2=j; }
                        else if (v > v3) { v4=v3;i4=i3; v3=v;i3=j; }
                        else if (v > v4) { v4=v;i4=j; }
                    }
                }
            }
            keep = (cand >= TOPK_);
            if (keep) tops = (1ull<<i0)|(1ull<<i1)|(1ull<<i2)|(1ull<<i3)|(1ull<<i4);
            float deg = (float)(dg > 0 ? dg : 1);
            float score = 1.0f / (1.0f + expf(-rs / deg));
            emaval = 0.45f + 0.1f * score;          // MOM*0.5 + (1-MOM)*score
        }
        if (wv == 0) { keep0[lane] = keep ? 1 : 0; tops0[lane] = tops; es[lane] = emaval; }
        else         { keep1[lane] = keep ? 1 : 0; tops1[lane] = tops; }
    }
    __syncthreads();
    if (wv < 2 && lane < m) {
        const unsigned long long* topsW = (wv == 0) ? tops0 : tops1;
        const unsigned char*     keepW = (wv == 0) ? keep0 : keep1;
        unsigned long long Mrow = 0ull;
        if (keep) {
            for (int j = 0; j < 64; ++j) {
                if (j == lane || !keepW[j]) continue;
                if (((tops >> j) & 1ull) || ((topsW[j] >> lane) & 1ull)) Mrow |= (1ull << j);
            }
        }
        if (wv == 0) M0s[lane] = Mrow; else M1s[lane] = Mrow;
    }
    __syncthreads();

    // ---- masked reduce (identical loop + reduce order to passing version) ----
    float fn = 0.0f, fd = 0.0f, fc = 0.0f;
    for (int idx = tid; idx < (m << 6); idx += NTH) {
        int i = idx >> 6, j = idx & 63;
        if (j >= m) continue;
        bool b0 = (M0s[i] >> j) & 1ull;
        bool b1 = (M1s[i] >> j) & 1ull;
        if (b0 | b1) {
            float v0 = b0 ? Gs0[i][j] : 0.0f;   // normalized+clipped in k_gram2
            float v1 = b1 ? Gs1[i][j] : 0.0f;
            float w = es[i] * es[j];
            float d = v1 - v0;
            fn = fmaf(d * d, w, fn);
            fd += w;
            fc += 1.0f;
        }
    }
    for (int off = 32; off > 0; off >>= 1) {
        fn += __shfl_down(fn, off);
        fd += __shfl_down(fd, off);
        fc += __shfl_down(fc, off);
    }
    if ((tid & 63) == 0) { red[wv * 3] = fn; red[wv * 3 + 1] = fd; red[wv * 3 + 2] = fc; }
    __syncthreads();
    if (tid == 0) {
        float* dst = partial + ((size_t)p * NLAB + c) * 4;
        dst[0] = red[0] + red[3] + red[6] + red[9];
        dst[1] = red[1] + red[4] + red[7] + red[10];
        dst[2] = red[2] + red[5] + red[8] + red[11];
    }
}

// Single-wave final reduction over 896 private slots (~14 KB, L2-hit).
__global__ void k_final(const float* __restrict__ partial, float* __restrict__ out)
{
    int tid = threadIdx.x;
    float total = 0.0f;
    for (int p = 0; p < NL - 1; ++p) {
        float n = 0.0f, d = 0.0f, cc = 0.0f;
        for (int c = tid; c < NLAB; c += 64) {
            const float* src = partial + ((size_t)p * NLAB + c) * 4;
            n += src[0]; d += src[1]; cc += src[2];
        }
        for (int off = 32; off > 0; off >>= 1) {
            n += __shfl_down(n, off);
            d += __shfl_down(d, off);
            cc += __shfl_down(cc, off);
        }
        if (tid == 0 && cc > 0.0f) total += n / fmaxf(d, 1e-8f);
    }
    if (tid == 0) out[0] = 16.0f * total / 7.0f;   // LAMBDA_ALIGN_K * sum / (L-1)
}

extern "C" void kernel_launch(void* const* d_in, const int* in_sizes, int n_in,
                              void* d_out, int out_size, void* d_ws, size_t ws_size,
                              hipStream_t stream) {
    const float* feats  = (const float*)d_in[0];
    const int*   labels = (const int*)d_in[1];
    // (sample_ids unused by the reference)
    char* w = (char*)d_ws;
    size_t gbytes = (size_t)NL * NLAB * GSTRIDE * 4;                 // 16,777,216
    float*    G       = (float*)(w);                                 // normalized grams
    float*    partial = (float*)(w + gbytes);                        // 14,336 B
    int*      cnt     = (int*)(w + gbytes + 14336);                  // 512 B
    unsigned long long* insub = (unsigned long long*)(w + gbytes + 14848);   // 1,024 B
    float*    out     = (float*)d_out;

    k_gram2  <<<dim3(NLAB, 4),      NTH, 0, stream>>>(feats, labels, G, cnt, insub);
    k_pairdec<<<dim3(NLAB, NL - 1), NTH, 0, stream>>>(G, cnt, insub, partial);
    k_final  <<<1, 64, 0, stream>>>(partial, out);
}

// Round 6
// 133.129 us; speedup vs baseline: 2.4279x; 1.0597x over previous
//
#include <hip/hip_runtime.h>
#include <cmath>

#define NB   2048
#define ND   512
#define NL   8
#define NLAB 128
#define MAXM 64
#define TOPK_ 5
#define NTH  256
#define MAXSLOT 9            // ceil(64*65/2 / 256)
#define GSTRIDE (MAXM*MAXM)  // 4096 floats per (label,layer) gram

// ---------------------------------------------------------------------------
// R17. Evidence so far: gram kernel is per-block latency-chain bound (R12/13/16
// block-count scaling), NOT dispatch/BW/bank-conflict bound. Suspect: the
// accumulator/pair-index arrays are indexed by a RUNTIME loop var -> compiler
// puts them in scratch (global memory); VGPR_Count=84 confirms (too low for
// 8 staging float4 + 18 accs). Scratch RMW per slot per chunk-round sits on
// the critical path. Fix: statically unroll the slot loop (compile-time s,
// active-flag guard) -> all slot state in VGPRs. Same FP order everywhere;
// k_pairdec / k_final / launcher are R13-exact (129.3us, absmax 0.0).
// ---------------------------------------------------------------------------
#define SLOT_DECL(s) int off##s = -1; int lds##s = 0; float4 pre##s;
#define SLOT_INIT(s) { int idx = tid + (s)*NTH; if (idx < (m << 5)) { \
    int i = idx >> 5, k4 = idx & 31; \
    off##s = (g_s[i] << 9) + (k4 << 2); \
    lds##s = i * 132 + (k4 << 2); \
    pre##s = *(const float4*)(X + off##s); } }
#define SLOT_STORE(s) if (off##s >= 0) *(float4*)(XtF + lds##s) = pre##s;
#define SLOT_FETCH(s, kcn) if (off##s >= 0) pre##s = *(const float4*)(X + off##s + (kcn));

__global__ __launch_bounds__(NTH) void k_gram(
    const float* __restrict__ feats, const int* __restrict__ labels,
    float* __restrict__ G, int* __restrict__ cnt,
    unsigned long long* __restrict__ insub)
{
    __shared__ int wsum[4];
    __shared__ int g_s[MAXM];
    __shared__ float Xt[MAXM][132];   // 132%4==0 -> aligned float4 rows; reused as 64x65 tile
    __shared__ float rinvp[64];
    __shared__ unsigned long long tops_s[64];
    __shared__ unsigned char keep_s[64];
    float* XtF = &Xt[0][0];
    int c = blockIdx.x, l = blockIdx.y, tid = threadIdx.x;
    int lane = tid & 63, wv = tid >> 6;

    // ---- bucket via wave scan (deterministic, index-ascending) ----
    int my[8]; int n = 0; int base_i = tid * 8;
    for (int t = 0; t < 8; ++t) {
        int i = base_i + t;
        if (labels[i] == c) my[n++] = i;
    }
    int scan = n;
    #pragma unroll
    for (int off = 1; off < 64; off <<= 1) {
        int v = __shfl_up(scan, off);
        if (lane >= off) scan += v;
    }
    if (lane == 63) wsum[wv] = scan;
    __syncthreads();
    int w0 = wsum[0], w1 = wsum[1], w2 = wsum[2], w3 = wsum[3];
    int m = w0 + w1 + w2 + w3; if (m > MAXM) m = MAXM;
    int base = (wv > 0 ? w0 : 0) + (wv > 1 ? w1 : 0) + (wv > 2 ? w2 : 0);
    int excl = base + scan - n;
    for (int t = 0; t < n; ++t) {
        int slot = excl + t;
        if (slot < MAXM) g_s[slot] = my[t];
    }
    if (l == 0 && tid == 0) cnt[c] = m;
    __syncthreads();
    if (m == 0) {
        if (l == 7 && tid == 0) insub[c] = 0ull;
        return;
    }

    const float* X = feats + (size_t)l * NB * ND;

    // ---- scalar staging slots; prefetch chunk 0 ----
    SLOT_DECL(0) SLOT_DECL(1) SLOT_DECL(2) SLOT_DECL(3)
    SLOT_DECL(4) SLOT_DECL(5) SLOT_DECL(6) SLOT_DECL(7)
    SLOT_INIT(0) SLOT_INIT(1) SLOT_INIT(2) SLOT_INIT(3)
    SLOT_INIT(4) SLOT_INIT(5) SLOT_INIT(6) SLOT_INIT(7)

    // ---- triangular slot decode, STATICALLY UNROLLED -> all state in VGPRs ----
    const int P = m * (m + 1) / 2;    // triangular incl. diag
    float acc0[MAXSLOT], acc1[MAXSLOT];
    int   ii_[MAXSLOT], jj_[MAXSLOT];   // ii_ < 0 -> inactive slot
    #pragma unroll
    for (int s = 0; s < MAXSLOT; ++s) {
        int p = tid + s * NTH;
        int iv = -1, jv = 0;
        if (p < P) {
            int i = (int)((sqrtf(8.0f * (float)p + 1.0f) - 1.0f) * 0.5f);
            while (((i + 1) * (i + 2)) / 2 <= p) ++i;
            while ((i * (i + 1)) / 2 > p) --i;
            iv = i; jv = p - (i * (i + 1)) / 2;
        }
        ii_[s] = iv; jj_[s] = jv;
        acc0[s] = 0.0f; acc1[s] = 0.0f;
    }

    // ---- pipelined K-loop: store staged regs, prefetch next, compute ----
    for (int kc = 0; kc < ND; kc += 128) {
        if (kc) __syncthreads();      // previous chunk's readers done
        SLOT_STORE(0) SLOT_STORE(1) SLOT_STORE(2) SLOT_STORE(3)
        SLOT_STORE(4) SLOT_STORE(5) SLOT_STORE(6) SLOT_STORE(7)
        __syncthreads();
        if (kc + 128 < ND) {
            int kcn = kc + 128;
            SLOT_FETCH(0, kcn) SLOT_FETCH(1, kcn) SLOT_FETCH(2, kcn) SLOT_FETCH(3, kcn)
            SLOT_FETCH(4, kcn) SLOT_FETCH(5, kcn) SLOT_FETCH(6, kcn) SLOT_FETCH(7, kcn)
        }
        #pragma unroll
        for (int s = 0; s < MAXSLOT; ++s) {
            if (ii_[s] >= 0) {
                const float* ra = &Xt[ii_[s]][0];
                const float* rb = &Xt[jj_[s]][0];
                float a0 = acc0[s], a1 = acc1[s];
                #pragma unroll
                for (int k4 = 0; k4 < 32; ++k4) {
                    float4 a = *(const float4*)(ra + (k4 << 2));
                    float4 b = *(const float4*)(rb + (k4 << 2));
                    a0 = fmaf(a.x, b.x, a0); a1 = fmaf(a.y, b.y, a1);
                    a0 = fmaf(a.z, b.z, a0); a1 = fmaf(a.w, b.w, a1);
                }
                acc0[s] = a0; acc1[s] = a1;
            }
        }
    }

    // ---- stage raw tile in LDS (reuse Xt), normalize in place, store ----
    float (*Gs)[65] = (float(*)[65])(&Xt[0][0]);
    __syncthreads();                  // all Xt readers done before overwrite
    #pragma unroll
    for (int s = 0; s < MAXSLOT; ++s) {
        if (ii_[s] >= 0) {
            float v = acc0[s] + acc1[s];
            Gs[ii_[s]][jj_[s]] = v; Gs[jj_[s]][ii_[s]] = v;
        }
    }
    if (tid < m) for (int j = m; j < 64; ++j) Gs[tid][j] = -2.0f;  // sentinel cols
    __syncthreads();
    if (tid < 64) rinvp[tid] = (tid < m) ? 1.0f / fmaxf(sqrtf(Gs[tid][tid]), 1e-8f) : 0.0f;
    __syncthreads();
    // normalize+clip in place: clip((raw*ri)*rj) -- exact op order of load_tile
    for (int idx = tid; idx < (m << 6); idx += NTH) {
        int i = idx >> 6, j = idx & 63;
        if (j < m) {
            float raw = Gs[i][j];
            Gs[i][j] = fminf(fmaxf(raw * rinvp[i] * rinvp[j], -1.0f), 1.0f);
        }
    }
    __syncthreads();
    // coalesced row write of the m live rows (cols >= m carry sentinel -2)
    float* Gc = G + ((size_t)l * NLAB + c) * GSTRIDE;
    for (int idx4 = tid; idx4 < (m << 4); idx4 += NTH) {
        int i = idx4 >> 4, j0 = (idx4 & 15) << 2;
        *(float4*)(Gc + i * MAXM + j0) = *(const float4*)&Gs[i][j0];
    }
    if (l != 7) return;

    // ---------- fused phase-1 (layer-7 blocks only), from normalized tile ----
    if (tid < 64) { keep_s[tid] = 0; tops_s[tid] = 0ull; }
    __syncthreads();
    unsigned long long tops = 0ull; bool keep = false;
    if (tid < m) {
        float v0=-1.f,v1=-1.f,v2=-1.f,v3=-1.f,v4=-1.f;
        int i0=0,i1=0,i2=0,i3=0,i4=0, cand=0;
        #pragma unroll 8
        for (int j = 0; j < 64; ++j) {
            float v = Gs[tid][j];          // normalized, or -2 sentinel
            if (v > 0.0f && j != tid) {
                ++cand;
                if      (v > v0) { v4=v3;i4=i3; v3=v2;i3=i2; v2=v1;i2=i1; v1=v0;i1=i0; v0=v;i0=j; }
                else if (v > v1) { v4=v3;i4=i3; v3=v2;i3=i2; v2=v1;i2=i1; v1=v;i1=j; }
                else if (v > v2) { v4=v3;i4=i3; v3=v2;i3=i2; v2=v;i2=j; }
                else if (v > v3) { v4=v3;i4=i3; v3=v;i3=j; }
                else if (v > v4) { v4=v;i4=j; }
            }
        }
        keep = (cand >= TOPK_);
        if (keep) tops = (1ull<<i0)|(1ull<<i1)|(1ull<<i2)|(1ull<<i3)|(1ull<<i4);
        keep_s[tid] = keep ? 1 : 0; tops_s[tid] = tops;
    }
    __syncthreads();
    unsigned long long Mrow = 0ull;
    if (tid < m && keep) {
        for (int j = 0; j < 64; ++j) {
            if (j == tid || !keep_s[j]) continue;
            if (((tops >> j) & 1ull) || ((tops_s[j] >> tid) & 1ull)) Mrow |= (1ull << j);
        }
    }
    if (tid < 64) {
        unsigned long long b = __ballot(Mrow != 0ull);
        if (tid == 0) insub[c] = b;
    }
}

// ---------------------------------------------------------------------------
// Per (label, pair p): load normalized tiles for layers p,p+1; decide(p) on
// wave 0 and decide(p+1) on wave 1 concurrently; masked pair reduce from LDS.
// ---------------------------------------------------------------------------
__global__ __launch_bounds__(NTH) void k_pairdec(
    const float* __restrict__ G, const int* __restrict__ cnt,
    const unsigned long long* __restrict__ insub,
    float* __restrict__ partial)   // [NL-1][NLAB][4]
{
    __shared__ float Gs0[64][65];
    __shared__ float Gs1[64][65];
    __shared__ unsigned long long tops0[64], tops1[64];
    __shared__ unsigned char keep0[64], keep1[64];
    __shared__ unsigned long long M0s[64], M1s[64];
    __shared__ float es[64];
    __shared__ float red[12];      // 4 waves x 3
    int c = blockIdx.x, p = blockIdx.y, tid = threadIdx.x;
    int lane = tid & 63, wv = tid >> 6;
    int m = cnt[c]; if (m > MAXM) m = MAXM;
    unsigned long long sub = insub[c];

    const float* G0 = G + ((size_t)p       * NLAB + c) * GSTRIDE;
    const float* G1 = G + ((size_t)(p + 1) * NLAB + c) * GSTRIDE;
    // load the two normalized tiles (m live rows x 16 float4 each)
    for (int idx4 = tid; idx4 < (m << 4); idx4 += NTH) {
        int i = idx4 >> 4, j0 = (idx4 & 15) << 2;
        *(float4*)&Gs0[i][j0] = *(const float4*)(G0 + i * MAXM + j0);
        *(float4*)&Gs1[i][j0] = *(const float4*)(G1 + i * MAXM + j0);
    }
    if (tid < 64)       { keep0[tid] = 0; tops0[tid] = 0ull; }
    else if (tid < 128) { keep1[tid - 64] = 0; tops1[tid - 64] = 0ull; }
    __syncthreads();

    // ---- decide: wave 0 -> layer p (also ema), wave 1 -> layer p+1 ----
    unsigned long long tops = 0ull; bool keep = false;
    if (wv < 2 && lane < m) {
        const float (*Gt)[65] = (wv == 0) ? Gs0 : Gs1;
        bool act = (sub >> lane) & 1ull;
        float emaval = 0.0f;
        if (act) {
            float v0=-1.f,v1=-1.f,v2=-1.f,v3=-1.f,v4=-1.f;
            int i0=0,i1=0,i2=0,i3=0,i4=0, cand=0, dg=0;
            float rs = 0.0f;
            #pragma unroll 8
            for (int j = 0; j < 64; ++j) {
                float v = Gt[lane][j];
                if (!((sub >> j) & 1ull)) v = -2.0f;
                if (v > 0.0f) {
                    rs += v; ++dg;                  // includes j == lane (diag ~ 1.0)
                    if (j != lane) {
                        ++cand;
                        if      (v > v0) { v4=v3;i4=i3; v3=v2;i3=i2; v2=v1;i2=i1; v1=v0;i1=i0; v0=v;i0=j; }
                        else if (v > v1) { v4=v3;i4=i3; v3=v2;i3=i2; v2=v1;i2=i1; v1=v;i1=j; }
                        else if (v > v2) { v4=v3;i4=i3; v3=v2;i3=i2; v2=v;i2=j; }
                        else if (v > v3) { v4=v3;i4=i3; v3=v;i3=j; }
                        else if (v > v4) { v4=v;i4=j; }
                    }
                }
            }
            keep = (cand >= TOPK_);
            if (keep) tops = (1ull<<i0)|(1ull<<i1)|(1ull<<i2)|(1ull<<i3)|(1ull<<i4);
            float deg = (float)(dg > 0 ? dg : 1);
            float score = 1.0f / (1.0f + expf(-rs / deg));
            emaval = 0.45f + 0.1f * score;          // MOM*0.5 + (1-MOM)*score
        }
        if (wv == 0) { keep0[lane] = keep ? 1 : 0; tops0[lane] = tops; es[lane] = emaval; }
        else         { keep1[lane] = keep ? 1 : 0; tops1[lane] = tops; }
    }
    __syncthreads();
    if (wv < 2 && lane < m) {
        const unsigned long long* topsW = (wv == 0) ? tops0 : tops1;
        const unsigned char*     keepW = (wv == 0) ? keep0 : keep1;
        unsigned long long Mrow = 0ull;
        if (keep) {
            for (int j = 0; j < 64; ++j) {
                if (j == lane || !keepW[j]) continue;
                if (((tops >> j) & 1ull) || ((topsW[j] >> lane) & 1ull)) Mrow |= (1ull << j);
            }
        }
        if (wv == 0) M0s[lane] = Mrow; else M1s[lane] = Mrow;
    }
    __syncthreads();

    // ---- masked reduce (identical loop + reduce order to passing k_pairs) ----
    float fn = 0.0f, fd = 0.0f, fc = 0.0f;
    for (int idx = tid; idx < (m << 6); idx += NTH) {
        int i = idx >> 6, j = idx & 63;
        if (j >= m) continue;
        bool b0 = (M0s[i] >> j) & 1ull;
        bool b1 = (M1s[i] >> j) & 1ull;
        if (b0 | b1) {
            float v0 = b0 ? Gs0[i][j] : 0.0f;   // normalized+clipped in k_gram
            float v1 = b1 ? Gs1[i][j] : 0.0f;
            float w = es[i] * es[j];
            float d = v1 - v0;
            fn = fmaf(d * d, w, fn);
            fd += w;
            fc += 1.0f;
        }
    }
    for (int off = 32; off > 0; off >>= 1) {
        fn += __shfl_down(fn, off);
        fd += __shfl_down(fd, off);
        fc += __shfl_down(fc, off);
    }
    if ((tid & 63) == 0) { red[wv * 3] = fn; red[wv * 3 + 1] = fd; red[wv * 3 + 2] = fc; }
    __syncthreads();
    if (tid == 0) {
        float* dst = partial + ((size_t)p * NLAB + c) * 4;
        dst[0] = red[0] + red[3] + red[6] + red[9];
        dst[1] = red[1] + red[4] + red[7] + red[10];
        dst[2] = red[2] + red[5] + red[8] + red[11];
    }
}

// Single-wave final reduction over 896 private slots (~14 KB, L2-hit).
__global__ void k_final(const float* __restrict__ partial, float* __restrict__ out)
{
    int tid = threadIdx.x;
    float total = 0.0f;
    for (int p = 0; p < NL - 1; ++p) {
        float n = 0.0f, d = 0.0f, cc = 0.0f;
        for (int c = tid; c < NLAB; c += 64) {
            const float* src = partial + ((size_t)p * NLAB + c) * 4;
            n += src[0]; d += src[1]; cc += src[2];
        }
        for (int off = 32; off > 0; off >>= 1) {
            n += __shfl_down(n, off);
            d += __shfl_down(d, off);
            cc += __shfl_down(cc, off);
        }
        if (tid == 0 && cc > 0.0f) total += n / fmaxf(d, 1e-8f);
    }
    if (tid == 0) out[0] = 16.0f * total / 7.0f;   // LAMBDA_ALIGN_K * sum / (L-1)
}

extern "C" void kernel_launch(void* const* d_in, const int* in_sizes, int n_in,
                              void* d_out, int out_size, void* d_ws, size_t ws_size,
                              hipStream_t stream) {
    const float* feats  = (const float*)d_in[0];
    const int*   labels = (const int*)d_in[1];
    // (sample_ids unused by the reference)
    char* w = (char*)d_ws;
    size_t gbytes = (size_t)NL * NLAB * GSTRIDE * 4;                 // 16,777,216
    float*    G       = (float*)(w);                                 // normalized grams
    float*    partial = (float*)(w + gbytes);                        // 14,336 B
    int*      cnt     = (int*)(w + gbytes + 14336);                  // 512 B
    unsigned long long* insub = (unsigned long long*)(w + gbytes + 14848);   // 1,024 B
    float*    out     = (float*)d_out;

    k_gram   <<<dim3(NLAB, NL),     NTH, 0, stream>>>(feats, labels, G, cnt, insub);
    k_pairdec<<<dim3(NLAB, NL - 1), NTH, 0, stream>>>(G, cnt, insub, partial);
    k_final  <<<1, 64, 0, stream>>>(partial, out);
}